// Round 4
// baseline (127.881 us; speedup 1.0000x reference)
//
#include <hip/hip_runtime.h>

typedef _Float16 f16x2 __attribute__((ext_vector_type(2)));
typedef __fp16  fp16x2 __attribute__((ext_vector_type(2)));

// Problem constants
constexpr int NKW  = 25, NK = 625;
constexpr int WPADR = 132;                  // reference padded width
constexpr int WPT   = 160;                  // padded halves per (ki,kj) weight row
constexpr int RST   = 35;                   // LDS row stride in uint2 (+1 anti-conflict)
constexpr int RTOT  = 132;                  // staged rows: 2 pad + 128 + 2 pad
constexpr int NITEM = RTOT * 32;            // 4224 staged float4 items

union U2H { unsigned int u; f16x2 h; fp16x2 p; };

// ---- gather: dense W -> f16 weights, zero-padded 16-slot rows, TRANSPOSED ----
__global__ void gather_wp(const float* __restrict__ W, _Float16* __restrict__ wgpT) {
    int t = blockIdx.x * 256 + threadIdx.x;
    if (t >= NK * WPT) return;
    int k = t / WPT, p = t % WPT;
    int di = p >> 4, s = p & 15;
    int ki = k / NKW, kj = k % NKW;
    int o = (5 * kj + 2) & 3;
    int j = s - o;
    float val = 0.f;
    if (j >= 0 && j < 10)
        val = W[(size_t)((ki * 5 + di) * WPADR + kj * 5 + j) * NK + k];
    wgpT[((size_t)(p >> 3) * NK + k) * 8 + (p & 7)] = (_Float16)val;
}

__device__ __forceinline__ float dot2acc(unsigned int a, unsigned int b, float c) {
    U2H ua, ub; ua.u = a; ub.u = b;
#if __has_builtin(__builtin_amdgcn_fdot2)
    return __builtin_amdgcn_fdot2(ua.h, ub.h, c, false);
#else
    return c + (float)ua.h.x * (float)ub.h.x + (float)ua.h.y * (float)ub.h.y;
#endif
}

// R17: SINGLE-VARIABLE EXPERIMENT vs R16 — de-spill via launch bounds.
// R16's stage/compute overlap was EXACTLY neutral (126.69->126.61) => the
// serialization wasn't the critical path. Theory: __launch_bounds__(256,4)
// caps the allocator at 128 VGPR/wave; peak live range (wq[10]=40 + t[4]=16
// + compiler-hoisted next-chunk weight loads +40 + addressing) > 128 =>
// scratch spills => hundreds of MB of hidden per-thread HBM traffic, shared
// by R15 AND R16 (explains exact neutrality). Fix: (256,2) caps at 256 VGPR
// -> no spills; actual occupancy still set by real usage (~90-150 VGPR) and
// LDS (36960B -> 4 blocks/CU max). Even at 2 blocks/CU, in-flight loads
// (32KB/CU) >> BW-latency product (9.2KB) so staging stays HBM-BW-bound.
// Everything else is byte-identical to R16 for clean attribution.
template <bool USE_WG>
__global__ __launch_bounds__(256, 2)
void lc2d_img(const float* __restrict__ x, const _Float16* __restrict__ wgpT,
              const float* __restrict__ Wfull,
              const float* __restrict__ bias, float* __restrict__ out) {
    __shared__ uint2 xs[RTOT * RST];        // 36960 B

    const int b    = blockIdx.x;            // one image per block
    const int tid  = threadIdx.x;
    const int lane = tid & 63;
    const int pairbase = (tid >> 6) * 32 + (lane & 31);  // 0..127
    const int half = lane >> 5;             // lane pair (l, l^32) shares pairbase
    const int di0  = half * 5;              // this thread's 5 di rows
    const float* xb = x + ((size_t)b << 14);

    // ---- staging helpers: 4 items/thread per batch (16 VGPR of tmp) ----
    auto stage_load4 = [&](int u0, float4* tmp) {
#pragma unroll
        for (int u = 0; u < 4; ++u) {
            const int i = tid + (u0 + u) * 256;
            tmp[u] = make_float4(0.f, 0.f, 0.f, 0.f);
            if (i < NITEM) {
                const int idx = i >> 5, q = i & 31, r = idx - 2;
                if (r >= 0 && r < 128)
                    tmp[u] = *reinterpret_cast<const float4*>(xb + (r << 7) + (q << 2));
            }
        }
    };
    auto stage_write4 = [&](int u0, const float4* tmp) {
#pragma unroll
        for (int u = 0; u < 4; ++u) {
            const int i = tid + (u0 + u) * 256;
            if (i < NITEM) {
                const int idx = i >> 5, q = (i & 31) + 1;
                U2H u0h, u1h;
                u0h.p = __builtin_amdgcn_cvt_pkrtz(tmp[u].x, tmp[u].y);
                u1h.p = __builtin_amdgcn_cvt_pkrtz(tmp[u].z, tmp[u].w);
                xs[idx * RST + q] = make_uint2(u0h.u, u1h.u);
            }
        }
    };

    // ---- weight chunk loader: coalesced uint4 from wgpT (or dense fallback) ----
    uint4 wq[10];
    float bv = 0.f;
    auto load_w = [&](int c) {
        const int pr = c * 128 + pairbase;
        if (pr >= NK) return;
        if constexpr (USE_WG) {
            const uint4* wt4 = reinterpret_cast<const uint4*>(wgpT);
#pragma unroll
            for (int j = 0; j < 10; ++j) wq[j] = wt4[(size_t)(half * 10 + j) * NK + pr];
        } else {
            const int ki = pr / 25, kj = pr - ki * 25;
            const int o = (5 * kj + 2) & 3;
#pragma unroll
            for (int j = 0; j < 10; ++j) {
                const int di = di0 + (j >> 1), pb = (j & 1) * 8;
                unsigned int uu[4];
#pragma unroll
                for (int m = 0; m < 4; ++m) {
                    float f0 = 0.f, f1 = 0.f;
                    const int j0 = pb + 2 * m - o, j1 = pb + 2 * m + 1 - o;
                    const size_t rowb = (size_t)((ki * 5 + di) * WPADR + kj * 5);
                    if (j0 >= 0 && j0 < 10) f0 = Wfull[(rowb + j0) * NK + pr];
                    if (j1 >= 0 && j1 < 10) f1 = Wfull[(rowb + j1) * NK + pr];
                    U2H u; u.p = __builtin_amdgcn_cvt_pkrtz(f0, f1);
                    uu[m] = u.u;
                }
                wq[j] = make_uint4(uu[0], uu[1], uu[2], uu[3]);
            }
        }
        if (half == 0) bv = bias[pr];
    };

    auto compute_chunk = [&](int c) {
        const int pr = c * 128 + pairbase;
        float acc0 = 0.f, acc1 = 0.f;
        if (pr < NK) {
            const int ki = pr / 25, kj = pr - ki * 25;
            const uint2* base = xs + (5 * ki + di0) * RST + ((5 * kj + 2) >> 2);
#pragma unroll
            for (int d = 0; d < 5; ++d) {
                const uint2* rowp = base + d * RST;
                const uint2 a0 = rowp[0], a1 = rowp[1], a2 = rowp[2], a3 = rowp[3];
                const uint4 wA = wq[2 * d], wB = wq[2 * d + 1];
                acc0 = dot2acc(a0.x, wA.x, acc0);
                acc1 = dot2acc(a0.y, wA.y, acc1);
                acc0 = dot2acc(a1.x, wA.z, acc0);
                acc1 = dot2acc(a1.y, wA.w, acc1);
                acc0 = dot2acc(a2.x, wB.x, acc0);
                acc1 = dot2acc(a2.y, wB.y, acc1);
                acc0 = dot2acc(a3.x, wB.z, acc0);
                acc1 = dot2acc(a3.y, wB.w, acc1);
            }
        }
        float acc = acc0 + acc1;
        float other = __shfl_xor(acc, 32, 64);
        if (pr < NK && half == 0)
            out[(size_t)b * NK + pr] = acc + other + bv;
    };

    // ---- boundary zeros: q=0 (left) and q=33 (right) of every row ----
    for (int i = tid; i < 2 * RTOT; i += 256)
        xs[(i >> 1) * RST + (i & 1) * 33] = make_uint2(0u, 0u);

    // ---- phase A: stage rows 0..63 (items 0..2047), weights chunk 0 ----
    {
        float4 t[4];
        stage_load4(0, t);  stage_write4(0, t);
        stage_load4(4, t);  stage_write4(4, t);
    }
    load_w(0);                              // in flight across the barrier
    __syncthreads();                        // rows 0..63 + zeros visible

    // ---- phase B: chunks 0-1 (rows <=59) overlapped with staging 64..131 ----
    {
        float4 t[4];
        stage_load4(8, t);                  // rows 64..95 in flight
        compute_chunk(0);
        load_w(1);
        stage_write4(8, t);                 // disjoint rows: no barrier needed
        stage_load4(12, t);                 // rows 96..127
        compute_chunk(1);
        load_w(2);
        stage_write4(12, t);
        // tail: items 4096..4223 (rows 128..131), tid<128 active
        float4 t1 = make_float4(0.f, 0.f, 0.f, 0.f);
        const int i16 = tid + 4096;
        if (i16 < NITEM) {
            const int idx = i16 >> 5, q = i16 & 31, r = idx - 2;
            if (r >= 0 && r < 128)
                t1 = *reinterpret_cast<const float4*>(xb + (r << 7) + (q << 2));
        }
        if (i16 < NITEM) {
            const int idx = i16 >> 5, q = (i16 & 31) + 1;
            U2H u0h, u1h;
            u0h.p = __builtin_amdgcn_cvt_pkrtz(t1.x, t1.y);
            u1h.p = __builtin_amdgcn_cvt_pkrtz(t1.z, t1.w);
            xs[idx * RST + q] = make_uint2(u0h.u, u1h.u);
        }
    }
    __syncthreads();                        // rows 64..131 visible

    // ---- phase C: chunks 2-4 (rows 50..131) ----
    compute_chunk(2);
    load_w(3);
    compute_chunk(3);
    load_w(4);
    compute_chunk(4);
}

extern "C" void kernel_launch(void* const* d_in, const int* in_sizes, int n_in,
                              void* d_out, int out_size, void* d_ws, size_t ws_size,
                              hipStream_t stream) {
    const float* x    = (const float*)d_in[0];
    const float* W    = (const float*)d_in[1];
    const float* bias = (const float*)d_in[2];
    float* out = (float*)d_out;

    const dim3 grid(1024);                  // one block per image, whole grid resident
    if (ws_size >= (size_t)NK * WPT * sizeof(_Float16)) {
        _Float16* wgpT = (_Float16*)d_ws;
        gather_wp<<<(NK * WPT + 255) / 256, 256, 0, stream>>>(W, wgpT);
        lc2d_img<true><<<grid, 256, 0, stream>>>(x, wgpT, W, bias, out);
    } else {
        lc2d_img<false><<<grid, 256, 0, stream>>>(x, nullptr, W, bias, out);
    }
}

// Round 5
// 127.747 us; speedup vs baseline: 1.0010x; 1.0010x over previous
//
#include <hip/hip_runtime.h>

typedef _Float16 f16x2 __attribute__((ext_vector_type(2)));
typedef __fp16  fp16x2 __attribute__((ext_vector_type(2)));

// Problem constants
constexpr int NKW  = 25, NK = 625;
constexpr int WPADR = 132;                  // reference padded width
constexpr int WPT   = 160;                  // padded halves per (ki,kj) weight row
constexpr int RST   = 35;                   // LDS row stride in uint2 (+1 anti-conflict)
constexpr int BROWS = 30;                   // rows per band (5 ki * 5 + 5 halo)
constexpr int BITEM = BROWS * 32;           // 960 float4 items per band
constexpr int NBAND = 5;                    // 5 bands x 125 outputs = 625

union U2H { unsigned int u; f16x2 h; fp16x2 p; };

// ---- gather: dense W -> f16 weights, zero-padded 16-slot rows, TRANSPOSED ----
// wgpT as uint4[20][625]; slot j of output k holds padded halves 8j..8j+7.
// Real data at in-row slot o..o+9, o = (5*kj+2) & 3. (verified earlier rounds)
__global__ void gather_wp(const float* __restrict__ W, _Float16* __restrict__ wgpT) {
    int t = blockIdx.x * 256 + threadIdx.x;
    if (t >= NK * WPT) return;
    int k = t / WPT, p = t % WPT;
    int di = p >> 4, s = p & 15;
    int ki = k / NKW, kj = k % NKW;
    int o = (5 * kj + 2) & 3;
    int j = s - o;
    float val = 0.f;
    if (j >= 0 && j < 10)
        val = W[(size_t)((ki * 5 + di) * WPADR + kj * 5 + j) * NK + k];
    wgpT[((size_t)(p >> 3) * NK + k) * 8 + (p & 7)] = (_Float16)val;
}

__device__ __forceinline__ float dot2acc(unsigned int a, unsigned int b, float c) {
    U2H ua, ub; ua.u = a; ub.u = b;
#if __has_builtin(__builtin_amdgcn_fdot2)
    return __builtin_amdgcn_fdot2(ua.h, ub.h, c, false);
#else
    return c + (float)ua.h.x * (float)ub.h.x + (float)ua.h.y * (float)ub.h.y;
#endif
}

// R18: BAND PIPELINE. Accounting (calibrated by R1's directly-measured 56.8us
// pipe<false>): fixed harness cost F=93.65us; R0 6-slab pipe ~24us; one-image
// kernel ~31us across 3 structurally-different variants (all NULL). The pipe
// beats img despite 2x the traffic -> traffic is NOT the limiter; the pipe's
// 8-deep stage||compute pipeline is. This kernel = img's minimal traffic +
// pipe's deep pipeline: one image per block, 5 row-bands (30 rows, 5 ki each),
// double-buffered LDS (2x8.4KB), stage(t+1) overlapped with compute(t),
// weights streamed per band right after compute frees wq. 1 barrier/band.
template <bool USE_WG>
__global__ __launch_bounds__(256, 4)
void lc2d_band(const float* __restrict__ x, const _Float16* __restrict__ wgpT,
               const float* __restrict__ Wfull,
               const float* __restrict__ bias, float* __restrict__ out) {
    __shared__ uint2 xs[2][BROWS * RST];    // 16800 B

    const int b    = blockIdx.x;            // one image per block
    const int tid  = threadIdx.x;
    const int lane = tid & 63;
    const int pairidx = (tid >> 6) * 32 + (lane & 31);   // 0..127
    const int half = lane >> 5;             // lane pair (l, l^32) shares pairidx
    const int di0  = half * 5;              // this thread's 5 di rows
    const bool active = pairidx < 125;      // 125 outputs per band
    const int ki_l = pairidx / 25;          // 0..4 within band
    const int kj   = pairidx - ki_l * 25;
    const float* xb = x + ((size_t)b << 14);

    // ---- band staging: 960 items = 3.75/thread (4 with guard) ----
    float4 tmp[4];
    auto band_load = [&](int t) {
        const int r0 = 25 * t - 2;
#pragma unroll
        for (int u = 0; u < 4; ++u) {
            const int i = tid + u * 256;
            tmp[u] = make_float4(0.f, 0.f, 0.f, 0.f);
            if (i < BITEM) {
                const int r = r0 + (i >> 5), q = i & 31;
                if (r >= 0 && r < 128)
                    tmp[u] = *reinterpret_cast<const float4*>(xb + (r << 7) + (q << 2));
            }
        }
    };
    auto band_write = [&](int buf) {
#pragma unroll
        for (int u = 0; u < 4; ++u) {
            const int i = tid + u * 256;
            if (i < BITEM) {
                const int idx = i >> 5, q = (i & 31) + 1;
                U2H u0h, u1h;
                u0h.p = __builtin_amdgcn_cvt_pkrtz(tmp[u].x, tmp[u].y);
                u1h.p = __builtin_amdgcn_cvt_pkrtz(tmp[u].z, tmp[u].w);
                xs[buf][idx * RST + q] = make_uint2(u0h.u, u1h.u);
            }
        }
    };

    // ---- per-band weights: coalesced uint4 from wgpT (or dense fallback) ----
    uint4 wq[10];
    float bv = 0.f;
    auto load_w = [&](int t) {
        if (!active) return;
        const int k = 125 * t + pairidx;    // global output index
        if constexpr (USE_WG) {
            const uint4* wt4 = reinterpret_cast<const uint4*>(wgpT);
#pragma unroll
            for (int j = 0; j < 10; ++j) wq[j] = wt4[(size_t)(half * 10 + j) * NK + k];
        } else {
            const int ki = 5 * t + ki_l;
            const int o = (5 * kj + 2) & 3;
#pragma unroll
            for (int j = 0; j < 10; ++j) {
                const int di = di0 + (j >> 1), pb = (j & 1) * 8;
                unsigned int uu[4];
#pragma unroll
                for (int m = 0; m < 4; ++m) {
                    float f0 = 0.f, f1 = 0.f;
                    const int j0 = pb + 2 * m - o, j1 = pb + 2 * m + 1 - o;
                    const size_t rowb = (size_t)((ki * 5 + di) * WPADR + kj * 5);
                    if (j0 >= 0 && j0 < 10) f0 = Wfull[(rowb + j0) * NK + k];
                    if (j1 >= 0 && j1 < 10) f1 = Wfull[(rowb + j1) * NK + k];
                    U2H u; u.p = __builtin_amdgcn_cvt_pkrtz(f0, f1);
                    uu[m] = u.u;
                }
                wq[j] = make_uint4(uu[0], uu[1], uu[2], uu[3]);
            }
        }
        if (half == 0) bv = bias[k];
    };

    auto compute = [&](int t, int buf) {
        float acc0 = 0.f, acc1 = 0.f;
        if (active) {
            // LOCAL band row: output row band-offset 5*ki_l + di0 + d, d=0..4
            const uint2* base = xs[buf] + (5 * ki_l + di0) * RST + ((5 * kj + 2) >> 2);
#pragma unroll
            for (int d = 0; d < 5; ++d) {
                const uint2* rowp = base + d * RST;
                const uint2 a0 = rowp[0], a1 = rowp[1], a2 = rowp[2], a3 = rowp[3];
                const uint4 wA = wq[2 * d], wB = wq[2 * d + 1];
                acc0 = dot2acc(a0.x, wA.x, acc0);
                acc1 = dot2acc(a0.y, wA.y, acc1);
                acc0 = dot2acc(a1.x, wA.z, acc0);
                acc1 = dot2acc(a1.y, wA.w, acc1);
                acc0 = dot2acc(a2.x, wB.x, acc0);
                acc1 = dot2acc(a2.y, wB.y, acc1);
                acc0 = dot2acc(a3.x, wB.z, acc0);
                acc1 = dot2acc(a3.y, wB.w, acc1);
            }
        }
        float acc = acc0 + acc1;
        float other = __shfl_xor(acc, 32, 64);
        if (active && half == 0)
            out[(size_t)b * NK + 125 * t + pairidx] = acc + other + bv;
    };

    // ---- boundary zeros, both buffers: slots q=0 and q=33 of all 30 rows ----
    for (int i = tid; i < 4 * BROWS; i += 256)   // 120 items, one pass
        xs[i & 1][(i >> 2) * RST + ((i >> 1) & 1) * 33] = make_uint2(0u, 0u);

    // ---- prologue: band 0 staged, weights 0 loaded ----
    band_load(0);
    band_write(0);
    load_w(0);
    __syncthreads();

    // ---- 5-band pipeline: stage(t+1) || compute(t) ----
#pragma unroll
    for (int t = 0; t < NBAND; ++t) {
        if (t + 1 < NBAND) band_load(t + 1);     // global loads in flight
        compute(t, t & 1);                       // LDS + wq (band t)
        if (t + 1 < NBAND) {
            load_w(t + 1);                       // wq free now; L2 loads
            band_write((t + 1) & 1);             // other buffer: race-free
            __syncthreads();                     // band t+1 visible
        }
    }
}

extern "C" void kernel_launch(void* const* d_in, const int* in_sizes, int n_in,
                              void* d_out, int out_size, void* d_ws, size_t ws_size,
                              hipStream_t stream) {
    const float* x    = (const float*)d_in[0];
    const float* W    = (const float*)d_in[1];
    const float* bias = (const float*)d_in[2];
    float* out = (float*)d_out;

    const dim3 grid(1024);                  // one block per image
    if (ws_size >= (size_t)NK * WPT * sizeof(_Float16)) {
        _Float16* wgpT = (_Float16*)d_ws;
        gather_wp<<<(NK * WPT + 255) / 256, 256, 0, stream>>>(W, wgpT);
        lc2d_band<true><<<grid, 256, 0, stream>>>(x, wgpT, W, bias, out);
    } else {
        lc2d_band<false><<<grid, 256, 0, stream>>>(x, nullptr, W, bias, out);
    }
}